// Round 1
// baseline (387.633 us; speedup 1.0000x reference)
//
#include <hip/hip_runtime.h>
#include <hip/hip_bf16.h>

// GAT layer: h = doc@W + Wb; s1 = h@a1, s2 = h@a2;
// score[i,j] = lrelu(s1[i]+s2[j]+ab); att = softmax_rows(score); out = lrelu(att@h)
// N=8192, IN=512, D=256. Outputs: out (8192*256) then att (8192*8192), fp32.

typedef __attribute__((ext_vector_type(4))) float f32x4;
typedef __attribute__((ext_vector_type(8))) short short8;
typedef __attribute__((ext_vector_type(4))) unsigned short ushort4v;

#define SLOPE 0.1f

__device__ __forceinline__ float lrelu(float x){ return fmaxf(x, SLOPE * x); }

// round-to-nearest-even fp32 -> bf16 (values are finite, positive where used)
__device__ __forceinline__ unsigned short f2bf(float f){
  union { float f; unsigned u; } v; v.f = f;
  unsigned r = (v.u + 0x7fffu + ((v.u >> 16) & 1u)) >> 16;
  return (unsigned short)r;
}

// ---------------- K1: h = doc @ W + Wb  (fp32), also ht = h^T in bf16 ----------------
// grid (4, 128): 64x64 tile per block, 256 threads, 4x4 per thread, k-chunk 16.
__global__ __launch_bounds__(256) void k_h(
    const float* __restrict__ doc, const float* __restrict__ W,
    const float* __restrict__ Wb, float* __restrict__ h,
    unsigned short* __restrict__ ht)
{
  __shared__ __align__(16) float At[16][68];  // A^T: [k][row], pitch 68 (16B-aligned rows, conflict-light)
  __shared__ __align__(16) float Bs[16][68];  // [k][col]
  const int t  = threadIdx.x;
  const int cb = blockIdx.x * 64;
  const int rb = blockIdx.y * 64;
  const int tx = t & 15, ty = t >> 4;

  float acc[4][4] = {};

  const int srow = t >> 2, skq = t & 3;   // A staging: 64 rows x (4x4 k)
  const int bk = t >> 4, bc = t & 15;     // B staging: 16 k x (16x4 cols)

  for (int kk = 0; kk < 512; kk += 16) {
    f32x4 av = *reinterpret_cast<const f32x4*>(doc + (size_t)(rb + srow) * 512 + kk + skq * 4);
    f32x4 wv = *reinterpret_cast<const f32x4*>(W + (size_t)(kk + bk) * 256 + cb + bc * 4);
    __syncthreads();  // previous chunk's LDS reads done
    At[skq * 4 + 0][srow] = av[0];
    At[skq * 4 + 1][srow] = av[1];
    At[skq * 4 + 2][srow] = av[2];
    At[skq * 4 + 3][srow] = av[3];
    *reinterpret_cast<f32x4*>(&Bs[bk][bc * 4]) = wv;
    __syncthreads();
#pragma unroll
    for (int k = 0; k < 16; ++k) {
      f32x4 a4 = *reinterpret_cast<const f32x4*>(&At[k][ty * 4]);
      f32x4 b4 = *reinterpret_cast<const f32x4*>(&Bs[k][tx * 4]);
#pragma unroll
      for (int i = 0; i < 4; ++i)
#pragma unroll
        for (int j = 0; j < 4; ++j)
          acc[i][j] = fmaf(a4[i], b4[j], acc[i][j]);
    }
  }

  float bias[4];
#pragma unroll
  for (int j = 0; j < 4; ++j) bias[j] = Wb[cb + tx * 4 + j];

#pragma unroll
  for (int i = 0; i < 4; ++i) {
    const int r = rb + ty * 4 + i;
    f32x4 o;
#pragma unroll
    for (int j = 0; j < 4; ++j) o[j] = acc[i][j] + bias[j];
    *reinterpret_cast<f32x4*>(h + (size_t)r * 256 + cb + tx * 4) = o;
  }
  // ht[c][r] bf16, rows are the fast dim -> ushort4 over 4 contiguous rows
#pragma unroll
  for (int j = 0; j < 4; ++j) {
    const int c = cb + tx * 4 + j;
    ushort4v u;
#pragma unroll
    for (int i = 0; i < 4; ++i) u[i] = f2bf(acc[i][j] + bias[j]);
    *reinterpret_cast<ushort4v*>(ht + (size_t)c * 8192 + rb + ty * 4) = u;
  }
}

// ---------------- K2: s1 = h @ a[:256], s2 = h @ a[256:] ----------------
// grid 256: block = 32 rows, wave = 8 rows
__global__ __launch_bounds__(256) void k_s12(
    const float* __restrict__ h, const float* __restrict__ a,
    float* __restrict__ s1, float* __restrict__ s2)
{
  const int t = threadIdx.x, w = t >> 6, l = t & 63;
  float a1[4], a2[4];
#pragma unroll
  for (int q = 0; q < 4; ++q) { a1[q] = a[l + q * 64]; a2[q] = a[256 + l + q * 64]; }
  const int rbase = blockIdx.x * 32 + w * 8;
  for (int rr = 0; rr < 8; ++rr) {
    const int r = rbase + rr;
    float v1 = 0.f, v2 = 0.f;
#pragma unroll
    for (int q = 0; q < 4; ++q) {
      float hv = h[(size_t)r * 256 + l + q * 64];
      v1 = fmaf(hv, a1[q], v1);
      v2 = fmaf(hv, a2[q], v2);
    }
#pragma unroll
    for (int off = 32; off > 0; off >>= 1) { v1 += __shfl_down(v1, off); v2 += __shfl_down(v2, off); }
    if (l == 0) { s1[r] = v1; s2[r] = v2; }
  }
}

// ---------------- K3: invZ[i] = 1 / sum_j exp(lrelu(s1[i]+s2[j]+ab)) ----------------
// grid 512: block = 16 rows, wave = 4 rows; s2 staged in LDS
__global__ __launch_bounds__(256) void k_z(
    const float* __restrict__ s1, const float* __restrict__ s2g,
    const float* __restrict__ abp, float* __restrict__ invZ)
{
  __shared__ __align__(16) float s2s[8192];
  const int t = threadIdx.x;
#pragma unroll
  for (int i = 0; i < 8; ++i)
    *reinterpret_cast<f32x4*>(&s2s[(i * 256 + t) * 4]) =
        *reinterpret_cast<const f32x4*>(s2g + (size_t)(i * 256 + t) * 4);
  __syncthreads();
  const int w = t >> 6, l = t & 63;
  const float ab = abp[0];
  const int rb = blockIdx.x * 16 + w * 4;
  for (int rr = 0; rr < 4; ++rr) {
    const int r = rb + rr;
    const float s1a = s1[r] + ab;
    float z = 0.f;
#pragma unroll 4
    for (int k = 0; k < 32; ++k) {
      f32x4 v = *reinterpret_cast<const f32x4*>(&s2s[(k * 64 + l) * 4]);
#pragma unroll
      for (int q = 0; q < 4; ++q) z += __expf(lrelu(s1a + v[q]));
    }
#pragma unroll
    for (int off = 32; off > 0; off >>= 1) z += __shfl_down(z, off);
    if (l == 0) invZ[r] = 1.0f / z;
  }
}

// ---------------- K4: att (global write) + out = lrelu(att @ h) via MFMA ----------------
// grid 256: block = 32 rows x all 8192 j. 4 waves, wave w owns cols w*64..w*64+63.
// A-fragments (att) generated in-register in MFMA layout: row = lane&15, k = (lane>>4)*8+q.
// B-fragments read directly from global ht (h^T bf16): 8 contiguous j per lane = 16B.
__global__ __launch_bounds__(256) void k_att(
    const float* __restrict__ s1, const float* __restrict__ s2g,
    const float* __restrict__ invZ, const float* __restrict__ abp,
    const unsigned short* __restrict__ ht,
    float* __restrict__ att, float* __restrict__ out)
{
  __shared__ __align__(16) float s2s[8192];
  __shared__ float s1as[32];
  __shared__ float izs[32];
  const int t = threadIdx.x;
  const int rb = blockIdx.x * 32;
#pragma unroll
  for (int i = 0; i < 8; ++i)
    *reinterpret_cast<f32x4*>(&s2s[(i * 256 + t) * 4]) =
        *reinterpret_cast<const f32x4*>(s2g + (size_t)(i * 256 + t) * 4);
  if (t < 32) { s1as[t] = s1[rb + t] + abp[0]; izs[t] = invZ[rb + t]; }
  __syncthreads();

  const int w = t >> 6, l = t & 63;
  const int lr = l & 15, lg = l >> 4;
  const int cb = w * 64;

  f32x4 acc[2][4];
#pragma unroll
  for (int rt = 0; rt < 2; ++rt)
#pragma unroll
    for (int ct = 0; ct < 4; ++ct) acc[rt][ct] = (f32x4){0.f, 0.f, 0.f, 0.f};

  const float s1a0 = s1as[lr],      s1a1 = s1as[16 + lr];
  const float iz0  = izs[lr],       iz1  = izs[16 + lr];

  for (int kk = 0; kk < 8192; kk += 32) {
    const int jb = kk + lg * 8;
    const f32x4 s2lo = *reinterpret_cast<const f32x4*>(&s2s[jb]);
    const f32x4 s2hi = *reinterpret_cast<const f32x4*>(&s2s[jb + 4]);

    short8 afr[2];
#pragma unroll
    for (int rt = 0; rt < 2; ++rt) {
      const float s1a = rt ? s1a1 : s1a0;
      const float iz  = rt ? iz1  : iz0;
      float p[8];
#pragma unroll
      for (int q = 0; q < 4; ++q) {
        p[q]     = __expf(lrelu(s1a + s2lo[q])) * iz;
        p[4 + q] = __expf(lrelu(s1a + s2hi[q])) * iz;
      }
      if (w == rt) {  // each att element stored exactly once (wave 0 -> rows 0..15, wave 1 -> 16..31)
        float* base = att + (size_t)(rb + rt * 16 + lr) * 8192 + jb;
        *reinterpret_cast<f32x4*>(base)     = (f32x4){p[0], p[1], p[2], p[3]};
        *reinterpret_cast<f32x4*>(base + 4) = (f32x4){p[4], p[5], p[6], p[7]};
      }
      union { short8 v; unsigned short u[8]; } af;
#pragma unroll
      for (int q = 0; q < 8; ++q) af.u[q] = f2bf(p[q]);
      afr[rt] = af.v;
    }

#pragma unroll
    for (int ct = 0; ct < 4; ++ct) {
      const short8 b = *reinterpret_cast<const short8*>(
          ht + (size_t)(cb + ct * 16 + lr) * 8192 + kk + lg * 8);
      acc[0][ct] = __builtin_amdgcn_mfma_f32_16x16x32_bf16(afr[0], b, acc[0][ct], 0, 0, 0);
      acc[1][ct] = __builtin_amdgcn_mfma_f32_16x16x32_bf16(afr[1], b, acc[1][ct], 0, 0, 0);
    }
  }

  // epilogue: C/D layout col = lane&15, row = (lane>>4)*4 + reg
#pragma unroll
  for (int rt = 0; rt < 2; ++rt)
#pragma unroll
    for (int ct = 0; ct < 4; ++ct)
#pragma unroll
      for (int q = 0; q < 4; ++q) {
        const int r = rb + rt * 16 + lg * 4 + q;
        const int c = cb + ct * 16 + lr;
        out[(size_t)r * 256 + c] = lrelu(acc[rt][ct][q]);
      }
}

extern "C" void kernel_launch(void* const* d_in, const int* in_sizes, int n_in,
                              void* d_out, int out_size, void* d_ws, size_t ws_size,
                              hipStream_t stream)
{
  const float* doc = (const float*)d_in[0];
  const float* W   = (const float*)d_in[1];
  const float* Wb  = (const float*)d_in[2];
  const float* a   = (const float*)d_in[3];
  const float* ab  = (const float*)d_in[4];

  float* out = (float*)d_out;                 // 8192*256
  float* att = out + (size_t)8192 * 256;      // 8192*8192

  // workspace layout (needs ~12.2 MB)
  char* ws = (char*)d_ws;
  float* h           = (float*)ws;                                   // 8 MB
  unsigned short* ht = (unsigned short*)(ws + (size_t)8 * 1024 * 1024); // 4 MB (h^T bf16)
  float* s1          = (float*)(ws + (size_t)12 * 1024 * 1024);
  float* s2          = s1 + 8192;
  float* iz          = s2 + 8192;

  hipLaunchKernelGGL(k_h,   dim3(4, 128), dim3(256), 0, stream, doc, W, Wb, h, ht);
  hipLaunchKernelGGL(k_s12, dim3(256),    dim3(256), 0, stream, h, a, s1, s2);
  hipLaunchKernelGGL(k_z,   dim3(512),    dim3(256), 0, stream, s1, s2, ab, iz);
  hipLaunchKernelGGL(k_att, dim3(256),    dim3(256), 0, stream, s1, s2, iz, ab, ht, att, out);
}

// Round 2
// 218.040 us; speedup vs baseline: 1.7778x; 1.7778x over previous
//
#include <hip/hip_runtime.h>
#include <hip/hip_bf16.h>

// GAT layer: h = doc@W + Wb; s1 = h@a1, s2 = h@a2;
// score[i,j] = lrelu(s1[i]+s2[j]+ab); att = softmax_rows(score); out = lrelu(att@h)
// N=8192, IN=512, D=256. Outputs: out (8192*256) then att (8192*8192), fp32.
//
// Key identity: exp(lrelu(s1a+s2j)) = (s2j >= -s1a) ? exp(s1a)*e2[j] : exp(.1*s1a)*e02[j]
// with e2[j]=exp(s2[j]), e02[j]=exp(.1*s2[j]) -> no transcendentals in the N^2 loops.

typedef __attribute__((ext_vector_type(4))) float f32x4;
typedef __attribute__((ext_vector_type(2))) float f32x2;
typedef __attribute__((ext_vector_type(8))) short short8;
typedef __attribute__((ext_vector_type(4))) unsigned short ushort4v;

#define SLOPE 0.1f
#define NROW 8192
#define DDIM 256

__device__ __forceinline__ float lrelu(float x){ return fmaxf(x, SLOPE * x); }

// round-to-nearest-even fp32 -> bf16
__device__ __forceinline__ unsigned short f2bf(float f){
  union { float f; unsigned u; } v; v.f = f;
  unsigned r = (v.u + 0x7fffu + ((v.u >> 16) & 1u)) >> 16;
  return (unsigned short)r;
}

// ---------------- K1: h = doc @ W + Wb (fp32) + ht = h^T bf16 ----------------
__global__ __launch_bounds__(256) void k_h(
    const float* __restrict__ doc, const float* __restrict__ W,
    const float* __restrict__ Wb, float* __restrict__ h,
    unsigned short* __restrict__ ht)
{
  __shared__ __align__(16) float At[16][68];
  __shared__ __align__(16) float Bs[16][68];
  const int t  = threadIdx.x;
  const int cb = blockIdx.x * 64;
  const int rb = blockIdx.y * 64;
  const int tx = t & 15, ty = t >> 4;

  float acc[4][4] = {};
  const int srow = t >> 2, skq = t & 3;
  const int bk = t >> 4, bc = t & 15;

  for (int kk = 0; kk < 512; kk += 16) {
    f32x4 av = *reinterpret_cast<const f32x4*>(doc + (size_t)(rb + srow) * 512 + kk + skq * 4);
    f32x4 wv = *reinterpret_cast<const f32x4*>(W + (size_t)(kk + bk) * 256 + cb + bc * 4);
    __syncthreads();
    At[skq * 4 + 0][srow] = av[0];
    At[skq * 4 + 1][srow] = av[1];
    At[skq * 4 + 2][srow] = av[2];
    At[skq * 4 + 3][srow] = av[3];
    *reinterpret_cast<f32x4*>(&Bs[bk][bc * 4]) = wv;
    __syncthreads();
#pragma unroll
    for (int k = 0; k < 16; ++k) {
      f32x4 a4 = *reinterpret_cast<const f32x4*>(&At[k][ty * 4]);
      f32x4 b4 = *reinterpret_cast<const f32x4*>(&Bs[k][tx * 4]);
#pragma unroll
      for (int i = 0; i < 4; ++i)
#pragma unroll
        for (int j = 0; j < 4; ++j)
          acc[i][j] = fmaf(a4[i], b4[j], acc[i][j]);
    }
  }

  float bias[4];
#pragma unroll
  for (int j = 0; j < 4; ++j) bias[j] = Wb[cb + tx * 4 + j];

#pragma unroll
  for (int i = 0; i < 4; ++i) {
    const int r = rb + ty * 4 + i;
    f32x4 o;
#pragma unroll
    for (int j = 0; j < 4; ++j) o[j] = acc[i][j] + bias[j];
    *reinterpret_cast<f32x4*>(h + (size_t)r * 256 + cb + tx * 4) = o;
  }
#pragma unroll
  for (int j = 0; j < 4; ++j) {
    const int c = cb + tx * 4 + j;
    ushort4v u;
#pragma unroll
    for (int i = 0; i < 4; ++i) u[i] = f2bf(acc[i][j] + bias[j]);
    *reinterpret_cast<ushort4v*>(ht + (size_t)c * 8192 + rb + ty * 4) = u;
  }
}

// ---------------- K2: s1,s2 + exp tables e2=exp(s2), e02=exp(.1*s2) ----------------
__global__ __launch_bounds__(256) void k_s12(
    const float* __restrict__ h, const float* __restrict__ a,
    float* __restrict__ s1, float* __restrict__ s2,
    float* __restrict__ e2, float* __restrict__ e02)
{
  const int t = threadIdx.x, w = t >> 6, l = t & 63;
  float a1[4], a2[4];
#pragma unroll
  for (int q = 0; q < 4; ++q) { a1[q] = a[l + q * 64]; a2[q] = a[256 + l + q * 64]; }
  const int rbase = blockIdx.x * 32 + w * 8;
  for (int rr = 0; rr < 8; ++rr) {
    const int r = rbase + rr;
    float v1 = 0.f, v2 = 0.f;
#pragma unroll
    for (int q = 0; q < 4; ++q) {
      float hv = h[(size_t)r * 256 + l + q * 64];
      v1 = fmaf(hv, a1[q], v1);
      v2 = fmaf(hv, a2[q], v2);
    }
#pragma unroll
    for (int off = 32; off > 0; off >>= 1) { v1 += __shfl_down(v1, off); v2 += __shfl_down(v2, off); }
    if (l == 0) {
      s1[r] = v1; s2[r] = v2;
      e2[r] = __expf(v2); e02[r] = __expf(SLOPE * v2);
    }
  }
}

// ---------------- K3: per-row Z via select trick -> rowinfo {E1*iz, E01*iz, T, iz} ----------------
// grid 512: 16 rows/block, wave = 4 rows; {e2,e02} interleaved in LDS
__global__ __launch_bounds__(256) void k_z(
    const float* __restrict__ s1, const float* __restrict__ e2g,
    const float* __restrict__ e02g, const float* __restrict__ abp,
    float* __restrict__ rowinfo)
{
  __shared__ __align__(16) f32x2 ep[8192];  // 64 KB
  const int t = threadIdx.x;
  for (int i = t; i < 8192; i += 256) ep[i] = (f32x2){e2g[i], e02g[i]};
  __syncthreads();
  const int w = t >> 6, l = t & 63;
  const float ab = abp[0];
  const int rb = blockIdx.x * 16 + w * 4;
  for (int rr = 0; rr < 4; ++rr) {
    const int r = rb + rr;
    const float s1a = s1[r] + ab;
    const float E1 = __expf(s1a), E01 = __expf(SLOPE * s1a), T = __expf(-s1a);
    float zA = 0.f, zB = 0.f;
#pragma unroll 4
    for (int i = l; i < 8192; i += 64) {
      f32x2 e = ep[i];
      const bool c = (e.x >= T);       // s2j >= -s1a  (e2 monotone in s2)
      zA += c ? e.x : 0.f;
      zB += c ? 0.f : e.y;
    }
#pragma unroll
    for (int off = 32; off > 0; off >>= 1) { zA += __shfl_down(zA, off); zB += __shfl_down(zB, off); }
    if (l == 0) {
      const float z = E1 * zA + E01 * zB;
      const float iz = 1.0f / z;
      f32x4 ri = (f32x4){E1 * iz, E01 * iz, T, iz};
      *reinterpret_cast<f32x4*>(rowinfo + (size_t)r * 4) = ri;
    }
  }
}

// ---------------- K4: att + partial out via MFMA, split-K ----------------
// grid (KS, 128). Block: 64 rows x 256 cols, k-chunk CHUNK = 8192/KS.
// Wave w: generates p (A-frags + att) for rows rb+w*16..+15 ONLY (no duplication),
// shares bf16 frags via LDS (double-buffered, 1 barrier/iter),
// computes acc for all 64 rows x cols [w*64, w*64+64).
__global__ __launch_bounds__(256, 4) void k_att(
    const float* __restrict__ rowinfo, const float* __restrict__ e2g,
    const float* __restrict__ e02g, const unsigned short* __restrict__ ht,
    float* __restrict__ att, float* __restrict__ part, int CHUNK)
{
  extern __shared__ __align__(16) char smem[];
  short8* pls = reinterpret_cast<short8*>(smem);          // [2][256] frags, 8 KB
  float* e2s  = reinterpret_cast<float*>(smem + 8192);    // CHUNK
  float* e02s = e2s + CHUNK;                               // CHUNK

  const int t = threadIdx.x, w = t >> 6, l = t & 63;
  const int lr = l & 15, lg = l >> 4;
  const int rb = blockIdx.y * 64;
  const int kbase = blockIdx.x * CHUNK;

  for (int i = t * 4; i < CHUNK; i += 1024) {
    *reinterpret_cast<f32x4*>(e2s + i)  = *reinterpret_cast<const f32x4*>(e2g + kbase + i);
    *reinterpret_cast<f32x4*>(e02s + i) = *reinterpret_cast<const f32x4*>(e02g + kbase + i);
  }
  const int prow = rb + w * 16 + lr;        // row this lane generates p for
  const f32x4 ri = *reinterpret_cast<const f32x4*>(rowinfo + (size_t)prow * 4);
  const float E1z = ri[0], E01z = ri[1], T = ri[2];
  float* attrow = att + (size_t)prow * 8192 + kbase;
  __syncthreads();

  f32x4 acc[4][4];
#pragma unroll
  for (int rt = 0; rt < 4; ++rt)
#pragma unroll
    for (int ct = 0; ct < 4; ++ct) acc[rt][ct] = (f32x4){0.f, 0.f, 0.f, 0.f};

  for (int kk = 0; kk < CHUNK; kk += 32) {
    const int par = (kk >> 5) & 1;
    const int jb = kk + lg * 8;
    const f32x4 e2a  = *reinterpret_cast<const f32x4*>(e2s + jb);
    const f32x4 e2b  = *reinterpret_cast<const f32x4*>(e2s + jb + 4);
    const f32x4 e02a = *reinterpret_cast<const f32x4*>(e02s + jb);
    const f32x4 e02b = *reinterpret_cast<const f32x4*>(e02s + jb + 4);

    float p[8];
#pragma unroll
    for (int q = 0; q < 4; ++q) {
      const bool ca = (e2a[q] >= T);
      p[q] = (ca ? E1z : E01z) * (ca ? e2a[q] : e02a[q]);
      const bool cb2 = (e2b[q] >= T);
      p[4 + q] = (cb2 ? E1z : E01z) * (cb2 ? e2b[q] : e02b[q]);
    }
    __builtin_nontemporal_store((f32x4){p[0], p[1], p[2], p[3]},
                                reinterpret_cast<f32x4*>(attrow + jb));
    __builtin_nontemporal_store((f32x4){p[4], p[5], p[6], p[7]},
                                reinterpret_cast<f32x4*>(attrow + jb + 4));
    union { short8 v; unsigned short u[8]; } pa;
#pragma unroll
    for (int q = 0; q < 8; ++q) pa.u[q] = f2bf(p[q]);
    pls[par * 256 + w * 64 + l] = pa.v;   // ds_write_b128
    __syncthreads();
    const short8 af0 = pls[par * 256 +   0 + l];
    const short8 af1 = pls[par * 256 +  64 + l];
    const short8 af2 = pls[par * 256 + 128 + l];
    const short8 af3 = pls[par * 256 + 192 + l];
#pragma unroll
    for (int ct = 0; ct < 4; ++ct) {
      const short8 b = *reinterpret_cast<const short8*>(
          ht + (size_t)(w * 64 + ct * 16 + lr) * 8192 + kbase + kk + lg * 8);
      acc[0][ct] = __builtin_amdgcn_mfma_f32_16x16x32_bf16(af0, b, acc[0][ct], 0, 0, 0);
      acc[1][ct] = __builtin_amdgcn_mfma_f32_16x16x32_bf16(af1, b, acc[1][ct], 0, 0, 0);
      acc[2][ct] = __builtin_amdgcn_mfma_f32_16x16x32_bf16(af2, b, acc[2][ct], 0, 0, 0);
      acc[3][ct] = __builtin_amdgcn_mfma_f32_16x16x32_bf16(af3, b, acc[3][ct], 0, 0, 0);
    }
  }

  // epilogue: raw partial sums (lrelu deferred to reduce)
  float* pb = part + (size_t)blockIdx.x * ((size_t)NROW * DDIM);
#pragma unroll
  for (int rt = 0; rt < 4; ++rt)
#pragma unroll
    for (int ct = 0; ct < 4; ++ct)
#pragma unroll
      for (int q = 0; q < 4; ++q)
        pb[(size_t)(rb + rt * 16 + lg * 4 + q) * 256 + w * 64 + ct * 16 + lr] = acc[rt][ct][q];
}

// ---------------- K5: out = lrelu(sum_k part[k]) ----------------
__global__ __launch_bounds__(256) void k_reduce(
    const float* __restrict__ part, float* __restrict__ out, int KS)
{
  const size_t idx = ((size_t)blockIdx.x * 256 + threadIdx.x) * 4;
  f32x4 s = *reinterpret_cast<const f32x4*>(part + idx);
  for (int k = 1; k < KS; ++k) {
    const f32x4 v = *reinterpret_cast<const f32x4*>(part + (size_t)k * NROW * DDIM + idx);
#pragma unroll
    for (int q = 0; q < 4; ++q) s[q] += v[q];
  }
#pragma unroll
  for (int q = 0; q < 4; ++q) s[q] = lrelu(s[q]);
  *reinterpret_cast<f32x4*>(out + idx) = s;
}

extern "C" void kernel_launch(void* const* d_in, const int* in_sizes, int n_in,
                              void* d_out, int out_size, void* d_ws, size_t ws_size,
                              hipStream_t stream)
{
  const float* doc = (const float*)d_in[0];
  const float* W   = (const float*)d_in[1];
  const float* Wb  = (const float*)d_in[2];
  const float* a   = (const float*)d_in[3];
  const float* ab  = (const float*)d_in[4];

  float* out = (float*)d_out;                 // 8192*256
  float* att = out + (size_t)8192 * 256;      // 8192*8192

  char* ws = (char*)d_ws;
  float* h           = (float*)ws;                                      // 8 MB
  unsigned short* ht = (unsigned short*)(ws + (size_t)8 * 1024 * 1024); // 4 MB
  char* tb           = ws + (size_t)12 * 1024 * 1024;
  float* s1  = (float*)tb;                 // 32 KB
  float* s2  = s1 + 8192;
  float* e2  = s2 + 8192;
  float* e02 = e2 + 8192;
  float* rowinfo = e02 + 8192;             // 128 KB
  const size_t base = (size_t)12 * 1024 * 1024 + 288 * 1024;
  const size_t partBytes = (size_t)NROW * DDIM * sizeof(float);  // 8 MB per slice

  int KS = 0;
  for (int c = 8; c >= 1; c >>= 1)
    if (base + (size_t)c * partBytes <= ws_size) { KS = c; break; }
  float* part = (KS > 0) ? (float*)(ws + base) : out;  // emergency in-place fallback
  if (KS == 0) KS = 1;
  const int CHUNK = NROW / KS;
  const size_t smem = 8192 + (size_t)2 * CHUNK * sizeof(float);

  hipLaunchKernelGGL(k_h,      dim3(4, 128),   dim3(256), 0,    stream, doc, W, Wb, h, ht);
  hipLaunchKernelGGL(k_s12,    dim3(256),      dim3(256), 0,    stream, h, a, s1, s2, e2, e02);
  hipLaunchKernelGGL(k_z,      dim3(512),      dim3(256), 0,    stream, s1, e2, e02, ab, rowinfo);
  hipLaunchKernelGGL(k_att,    dim3(KS, 128),  dim3(256), smem, stream, rowinfo, e2, e02, ht, att, part, CHUNK);
  hipLaunchKernelGGL(k_reduce, dim3(2048),     dim3(256), 0,    stream, part, out, KS);
}

// Round 3
// 187.195 us; speedup vs baseline: 2.0707x; 1.1648x over previous
//
#include <hip/hip_runtime.h>
#include <hip/hip_bf16.h>

// GAT layer: h = doc@W + Wb; s1 = h@a1, s2 = h@a2;
// score[i,j] = lrelu(s1[i]+s2[j]+ab); att = softmax_rows(score); out = lrelu(att@h)
// N=8192, IN=512, D=256. Outputs: out (8192*256) then att (8192*8192), fp32.
//
// Key identity: exp(lrelu(s1a+s2j)) = (s2j >= -s1a) ? exp(s1a)*e2[j] : exp(.1*s1a)*e02[j]
// with e2[j]=exp(s2[j]), e02[j]=exp(.1*s2[j]) -> no transcendentals in the N^2 loops.

typedef __attribute__((ext_vector_type(4))) float f32x4;
typedef __attribute__((ext_vector_type(2))) float f32x2;
typedef __attribute__((ext_vector_type(8))) short short8;
typedef __attribute__((ext_vector_type(4))) unsigned short ushort4v;

#define SLOPE 0.1f
#define NROW 8192
#define DDIM 256

__device__ __forceinline__ float lrelu(float x){ return fmaxf(x, SLOPE * x); }

// round-to-nearest-even fp32 -> bf16
__device__ __forceinline__ unsigned short f2bf(float f){
  union { float f; unsigned u; } v; v.f = f;
  unsigned r = (v.u + 0x7fffu + ((v.u >> 16) & 1u)) >> 16;
  return (unsigned short)r;
}

// ---------------- K1: h = doc @ W + Wb (fp32) + ht = h^T bf16 ----------------
__global__ __launch_bounds__(256) void k_h(
    const float* __restrict__ doc, const float* __restrict__ W,
    const float* __restrict__ Wb, float* __restrict__ h,
    unsigned short* __restrict__ ht)
{
  __shared__ __align__(16) float At[16][68];
  __shared__ __align__(16) float Bs[16][68];
  const int t  = threadIdx.x;
  const int cb = blockIdx.x * 64;
  const int rb = blockIdx.y * 64;
  const int tx = t & 15, ty = t >> 4;

  float acc[4][4] = {};
  const int srow = t >> 2, skq = t & 3;
  const int bk = t >> 4, bc = t & 15;

  for (int kk = 0; kk < 512; kk += 16) {
    f32x4 av = *reinterpret_cast<const f32x4*>(doc + (size_t)(rb + srow) * 512 + kk + skq * 4);
    f32x4 wv = *reinterpret_cast<const f32x4*>(W + (size_t)(kk + bk) * 256 + cb + bc * 4);
    __syncthreads();
    At[skq * 4 + 0][srow] = av[0];
    At[skq * 4 + 1][srow] = av[1];
    At[skq * 4 + 2][srow] = av[2];
    At[skq * 4 + 3][srow] = av[3];
    *reinterpret_cast<f32x4*>(&Bs[bk][bc * 4]) = wv;
    __syncthreads();
#pragma unroll
    for (int k = 0; k < 16; ++k) {
      f32x4 a4 = *reinterpret_cast<const f32x4*>(&At[k][ty * 4]);
      f32x4 b4 = *reinterpret_cast<const f32x4*>(&Bs[k][tx * 4]);
#pragma unroll
      for (int i = 0; i < 4; ++i)
#pragma unroll
        for (int j = 0; j < 4; ++j)
          acc[i][j] = fmaf(a4[i], b4[j], acc[i][j]);
    }
  }

  float bias[4];
#pragma unroll
  for (int j = 0; j < 4; ++j) bias[j] = Wb[cb + tx * 4 + j];

#pragma unroll
  for (int i = 0; i < 4; ++i) {
    const int r = rb + ty * 4 + i;
    f32x4 o;
#pragma unroll
    for (int j = 0; j < 4; ++j) o[j] = acc[i][j] + bias[j];
    *reinterpret_cast<f32x4*>(h + (size_t)r * 256 + cb + tx * 4) = o;
  }
#pragma unroll
  for (int j = 0; j < 4; ++j) {
    const int c = cb + tx * 4 + j;
    ushort4v u;
#pragma unroll
    for (int i = 0; i < 4; ++i) u[i] = f2bf(acc[i][j] + bias[j]);
    *reinterpret_cast<ushort4v*>(ht + (size_t)c * 8192 + rb + ty * 4) = u;
  }
}

// ---------------- K2: s1,s2 + exp tables e2=exp(s2), e02=exp(.1*s2) ----------------
__global__ __launch_bounds__(256) void k_s12(
    const float* __restrict__ h, const float* __restrict__ a,
    float* __restrict__ s1, float* __restrict__ s2,
    float* __restrict__ e2, float* __restrict__ e02)
{
  const int t = threadIdx.x, w = t >> 6, l = t & 63;
  float a1[4], a2[4];
#pragma unroll
  for (int q = 0; q < 4; ++q) { a1[q] = a[l + q * 64]; a2[q] = a[256 + l + q * 64]; }
  const int rbase = blockIdx.x * 32 + w * 8;
  for (int rr = 0; rr < 8; ++rr) {
    const int r = rbase + rr;
    float v1 = 0.f, v2 = 0.f;
#pragma unroll
    for (int q = 0; q < 4; ++q) {
      float hv = h[(size_t)r * 256 + l + q * 64];
      v1 = fmaf(hv, a1[q], v1);
      v2 = fmaf(hv, a2[q], v2);
    }
#pragma unroll
    for (int off = 32; off > 0; off >>= 1) { v1 += __shfl_down(v1, off); v2 += __shfl_down(v2, off); }
    if (l == 0) {
      s1[r] = v1; s2[r] = v2;
      e2[r] = __expf(v2); e02[r] = __expf(SLOPE * v2);
    }
  }
}

// ---------------- K3: per-row Z via select trick -> rowinfo {E1*iz, E01*iz, T, iz} ----------------
__global__ __launch_bounds__(256) void k_z(
    const float* __restrict__ s1, const float* __restrict__ e2g,
    const float* __restrict__ e02g, const float* __restrict__ abp,
    float* __restrict__ rowinfo)
{
  __shared__ __align__(16) f32x2 ep[8192];  // 64 KB
  const int t = threadIdx.x;
  for (int i = t; i < 8192; i += 256) ep[i] = (f32x2){e2g[i], e02g[i]};
  __syncthreads();
  const int w = t >> 6, l = t & 63;
  const float ab = abp[0];
  const int rb = blockIdx.x * 16 + w * 4;
  for (int rr = 0; rr < 4; ++rr) {
    const int r = rb + rr;
    const float s1a = s1[r] + ab;
    const float E1 = __expf(s1a), E01 = __expf(SLOPE * s1a), T = __expf(-s1a);
    float zA = 0.f, zB = 0.f;
#pragma unroll 4
    for (int i = l; i < 8192; i += 64) {
      f32x2 e = ep[i];
      const bool c = (e.x >= T);       // s2j >= -s1a  (e2 monotone in s2)
      zA += c ? e.x : 0.f;
      zB += c ? 0.f : e.y;
    }
#pragma unroll
    for (int off = 32; off > 0; off >>= 1) { zA += __shfl_down(zA, off); zB += __shfl_down(zB, off); }
    if (l == 0) {
      const float z = E1 * zA + E01 * zB;
      const float iz = 1.0f / z;
      f32x4 ri = (f32x4){E1 * iz, E01 * iz, T, iz};
      *reinterpret_cast<f32x4*>(rowinfo + (size_t)r * 4) = ri;
    }
  }
}

// ---------------- K4: att + partial out via MFMA, split-K ----------------
// grid (KS, 128). Block: 64 rows x 256 cols, k-chunk CHUNK = 8192/KS.
// Wave w generates p (A-frags + att) for rows rb+w*16..+15 only; frags shared
// via double-buffered LDS. Barrier = raw s_barrier + lgkmcnt(0) ONLY (no vmcnt
// drain -> nontemporal att stores stay in flight across iterations).
__global__ __launch_bounds__(256, 4) void k_att(
    const float* __restrict__ rowinfo, const float* __restrict__ e2g,
    const float* __restrict__ e02g, const unsigned short* __restrict__ ht,
    float* __restrict__ att, float* __restrict__ part, int CHUNK)
{
  extern __shared__ __align__(16) char smem[];
  short8* pls = reinterpret_cast<short8*>(smem);          // [2][256] frags, 8 KB
  float* e2s  = reinterpret_cast<float*>(smem + 8192);    // CHUNK
  float* e02s = e2s + CHUNK;                               // CHUNK

  const int t = threadIdx.x, w = t >> 6, l = t & 63;
  const int lr = l & 15, lg = l >> 4;
  const int rb = blockIdx.y * 64;
  const int kbase = blockIdx.x * CHUNK;

  for (int i = t * 4; i < CHUNK; i += 1024) {
    *reinterpret_cast<f32x4*>(e2s + i)  = *reinterpret_cast<const f32x4*>(e2g + kbase + i);
    *reinterpret_cast<f32x4*>(e02s + i) = *reinterpret_cast<const f32x4*>(e02g + kbase + i);
  }
  const int prow = rb + w * 16 + lr;        // row this lane generates p for
  const f32x4 ri = *reinterpret_cast<const f32x4*>(rowinfo + (size_t)prow * 4);
  const float E1z = ri[0], E01z = ri[1], T = ri[2];
  float* attrow = att + (size_t)prow * 8192 + kbase;
  __syncthreads();

  f32x4 acc[4][4];
#pragma unroll
  for (int rt = 0; rt < 4; ++rt)
#pragma unroll
    for (int ct = 0; ct < 4; ++ct) acc[rt][ct] = (f32x4){0.f, 0.f, 0.f, 0.f};

  for (int kk = 0; kk < CHUNK; kk += 32) {
    const int par = (kk >> 5) & 1;
    const int jb = kk + lg * 8;

    // issue B-fragment loads early (L2-resident ht) so latency hides under p-gen
    const unsigned short* hb = ht + (size_t)(w * 64 + lr) * 8192 + kbase + kk + lg * 8;
    const short8 b0 = *reinterpret_cast<const short8*>(hb);
    const short8 b1 = *reinterpret_cast<const short8*>(hb + (size_t)16 * 8192);
    const short8 b2 = *reinterpret_cast<const short8*>(hb + (size_t)32 * 8192);
    const short8 b3 = *reinterpret_cast<const short8*>(hb + (size_t)48 * 8192);

    const f32x4 e2a  = *reinterpret_cast<const f32x4*>(e2s + jb);
    const f32x4 e2b  = *reinterpret_cast<const f32x4*>(e2s + jb + 4);
    const f32x4 e02a = *reinterpret_cast<const f32x4*>(e02s + jb);
    const f32x4 e02b = *reinterpret_cast<const f32x4*>(e02s + jb + 4);

    float p[8];
#pragma unroll
    for (int q = 0; q < 4; ++q) {
      const bool ca = (e2a[q] >= T);
      p[q] = (ca ? E1z : E01z) * (ca ? e2a[q] : e02a[q]);
      const bool cb2 = (e2b[q] >= T);
      p[4 + q] = (cb2 ? E1z : E01z) * (cb2 ? e2b[q] : e02b[q]);
    }
    __builtin_nontemporal_store((f32x4){p[0], p[1], p[2], p[3]},
                                reinterpret_cast<f32x4*>(attrow + jb));
    __builtin_nontemporal_store((f32x4){p[4], p[5], p[6], p[7]},
                                reinterpret_cast<f32x4*>(attrow + jb + 4));
    union { short8 v; unsigned short u[8]; } pa;
#pragma unroll
    for (int q = 0; q < 8; ++q) pa.u[q] = f2bf(p[q]);
    pls[par * 256 + w * 64 + l] = pa.v;   // ds_write_b128

    // LDS handoff barrier WITHOUT vmcnt drain (att stores stay in flight)
    asm volatile("s_waitcnt lgkmcnt(0)\n\ts_barrier" ::: "memory");

    const short8 af0 = pls[par * 256 +   0 + l];
    const short8 af1 = pls[par * 256 +  64 + l];
    const short8 af2 = pls[par * 256 + 128 + l];
    const short8 af3 = pls[par * 256 + 192 + l];

    __builtin_amdgcn_s_setprio(1);
    acc[0][0] = __builtin_amdgcn_mfma_f32_16x16x32_bf16(af0, b0, acc[0][0], 0, 0, 0);
    acc[1][0] = __builtin_amdgcn_mfma_f32_16x16x32_bf16(af1, b0, acc[1][0], 0, 0, 0);
    acc[2][0] = __builtin_amdgcn_mfma_f32_16x16x32_bf16(af2, b0, acc[2][0], 0, 0, 0);
    acc[3][0] = __builtin_amdgcn_mfma_f32_16x16x32_bf16(af3, b0, acc[3][0], 0, 0, 0);
    acc[0][1] = __builtin_amdgcn_mfma_f32_16x16x32_bf16(af0, b1, acc[0][1], 0, 0, 0);
    acc[1][1] = __builtin_amdgcn_mfma_f32_16x16x32_bf16(af1, b1, acc[1][1], 0, 0, 0);
    acc[2][1] = __builtin_amdgcn_mfma_f32_16x16x32_bf16(af2, b1, acc[2][1], 0, 0, 0);
    acc[3][1] = __builtin_amdgcn_mfma_f32_16x16x32_bf16(af3, b1, acc[3][1], 0, 0, 0);
    acc[0][2] = __builtin_amdgcn_mfma_f32_16x16x32_bf16(af0, b2, acc[0][2], 0, 0, 0);
    acc[1][2] = __builtin_amdgcn_mfma_f32_16x16x32_bf16(af1, b2, acc[1][2], 0, 0, 0);
    acc[2][2] = __builtin_amdgcn_mfma_f32_16x16x32_bf16(af2, b2, acc[2][2], 0, 0, 0);
    acc[3][2] = __builtin_amdgcn_mfma_f32_16x16x32_bf16(af3, b2, acc[3][2], 0, 0, 0);
    acc[0][3] = __builtin_amdgcn_mfma_f32_16x16x32_bf16(af0, b3, acc[0][3], 0, 0, 0);
    acc[1][3] = __builtin_amdgcn_mfma_f32_16x16x32_bf16(af1, b3, acc[1][3], 0, 0, 0);
    acc[2][3] = __builtin_amdgcn_mfma_f32_16x16x32_bf16(af2, b3, acc[2][3], 0, 0, 0);
    acc[3][3] = __builtin_amdgcn_mfma_f32_16x16x32_bf16(af3, b3, acc[3][3], 0, 0, 0);
    __builtin_amdgcn_s_setprio(0);
  }

  // epilogue: raw partial sums (lrelu deferred to reduce)
  float* pb = part + (size_t)blockIdx.x * ((size_t)NROW * DDIM);
#pragma unroll
  for (int rt = 0; rt < 4; ++rt)
#pragma unroll
    for (int ct = 0; ct < 4; ++ct)
#pragma unroll
      for (int q = 0; q < 4; ++q)
        pb[(size_t)(rb + rt * 16 + lg * 4 + q) * 256 + w * 64 + ct * 16 + lr] = acc[rt][ct][q];
}

// ---------------- K5: out = lrelu(sum_k part[k]) ----------------
__global__ __launch_bounds__(256) void k_reduce(
    const float* __restrict__ part, float* __restrict__ out, int KS)
{
  const size_t idx = ((size_t)blockIdx.x * 256 + threadIdx.x) * 4;
  f32x4 s = *reinterpret_cast<const f32x4*>(part + idx);
  for (int k = 1; k < KS; ++k) {
    const f32x4 v = *reinterpret_cast<const f32x4*>(part + (size_t)k * NROW * DDIM + idx);
#pragma unroll
    for (int q = 0; q < 4; ++q) s[q] += v[q];
  }
#pragma unroll
  for (int q = 0; q < 4; ++q) s[q] = lrelu(s[q]);
  *reinterpret_cast<f32x4*>(out + idx) = s;
}

extern "C" void kernel_launch(void* const* d_in, const int* in_sizes, int n_in,
                              void* d_out, int out_size, void* d_ws, size_t ws_size,
                              hipStream_t stream)
{
  const float* doc = (const float*)d_in[0];
  const float* W   = (const float*)d_in[1];
  const float* Wb  = (const float*)d_in[2];
  const float* a   = (const float*)d_in[3];
  const float* ab  = (const float*)d_in[4];

  float* out = (float*)d_out;                 // 8192*256
  float* att = out + (size_t)8192 * 256;      // 8192*8192

  char* ws = (char*)d_ws;
  float* h           = (float*)ws;                                      // 8 MB
  unsigned short* ht = (unsigned short*)(ws + (size_t)8 * 1024 * 1024); // 4 MB
  char* tb           = ws + (size_t)12 * 1024 * 1024;
  float* s1  = (float*)tb;                 // 32 KB
  float* s2  = s1 + 8192;
  float* e2  = s2 + 8192;
  float* e02 = e2 + 8192;
  float* rowinfo = e02 + 8192;             // 128 KB
  const size_t base = (size_t)12 * 1024 * 1024 + 288 * 1024;
  const size_t partBytes = (size_t)NROW * DDIM * sizeof(float);  // 8 MB per slice

  int KS = 0;
  for (int c = 8; c >= 1; c >>= 1)
    if (base + (size_t)c * partBytes <= ws_size) { KS = c; break; }
  float* part = (KS > 0) ? (float*)(ws + base) : out;  // emergency in-place fallback
  if (KS == 0) KS = 1;
  const int CHUNK = NROW / KS;
  const size_t smem = 8192 + (size_t)2 * CHUNK * sizeof(float);

  hipLaunchKernelGGL(k_h,      dim3(4, 128),   dim3(256), 0,    stream, doc, W, Wb, h, ht);
  hipLaunchKernelGGL(k_s12,    dim3(256),      dim3(256), 0,    stream, h, a, s1, s2, e2, e02);
  hipLaunchKernelGGL(k_z,      dim3(512),      dim3(256), 0,    stream, s1, e2, e02, ab, rowinfo);
  hipLaunchKernelGGL(k_att,    dim3(KS, 128),  dim3(256), smem, stream, rowinfo, e2, e02, ht, att, part, CHUNK);
  hipLaunchKernelGGL(k_reduce, dim3(2048),     dim3(256), 0,    stream, part, out, KS);
}